// Round 7
// baseline (408.065 us; speedup 1.0000x reference)
//
#include <hip/hip_runtime.h>
#include <math.h>

typedef __bf16 bf16;
typedef __bf16 bf16x8 __attribute__((ext_vector_type(8)));
typedef __bf16 bf16x4 __attribute__((ext_vector_type(4)));
typedef float f32x4 __attribute__((ext_vector_type(4)));

constexpr int cB = 256, cN = 256, cF = 128, cO = 256;
constexpr int BN = cB * cN;
constexpr float D2_FLOOR = 1e-12f;
constexpr float EPS_F = 1.401298464324817e-45f;  // np.spacing(float32(0))

// ---------------- workspace byte offsets ----------------
constexpr size_t OFF_X0  = 0;                                   // bf16 [BN][128]
constexpr size_t OFF_X0T = OFF_X0 + (size_t)BN * 128 * 2;       // bf16 [B][128][256]
constexpr size_t OFF_LB  = OFF_X0T + (size_t)cB * cF * cN * 2;  // bf16 [B][256][256]
constexpr size_t OFF_WB  = OFF_LB + (size_t)cB * cN * cN * 2;   // bf16 [B][256][256]
constexpr size_t OFF_WT  = OFF_WB + (size_t)cB * cN * cN * 2;   // bf16 [256][512]
constexpr size_t OFF_MT  = OFF_WT + 512 * 256 * 2;              // bf16 [128][128]
constexpr size_t OFF_DEG = OFF_MT + 128 * 128 * 2;              // f32 [BN]

// Direct global->VGPR MFMA fragment load: p = base of 16-row granule, ld in elems.
// lane l: row (l&15), k-slots k0 + 8*(l>>4) .. +7.
__device__ __forceinline__ bf16x8 gfrag(const bf16* __restrict__ p, int ld,
                                        int lane, int k0) {
  return *(const bf16x8*)(p + (size_t)(lane & 15) * ld + k0 + 8 * (lane >> 4));
}

__device__ __forceinline__ f32x4 mfma(bf16x8 a, bf16x8 b, f32x4 c) {
  return __builtin_amdgcn_mfma_f32_16x16x32_bf16(a, b, c, 0, 0, 0);
}

__device__ __forceinline__ void gll16(const void* g, void* l) {
  __builtin_amdgcn_global_load_lds((const __attribute__((address_space(1))) void*)g,
                                   (__attribute__((address_space(3))) void*)l, 16, 0, 0);
}

// ---------------- k_prep: mask+convert; write X0 [n][128] and x0T [f][n] ----------
__global__ __launch_bounds__(256) void k_prep(const float* __restrict__ x,
                                              const int* __restrict__ na_p,
                                              bf16* __restrict__ X0,
                                              bf16* __restrict__ x0T) {
  __shared__ __align__(16) bf16 T[64][132];
  int b = blockIdx.x >> 2, i0 = (blockIdx.x & 3) * 64;
  int tid = threadIdx.x;
  int na = na_p[b];
#pragma unroll
  for (int it = 0; it < 8; ++it) {
    int ir = it * 8 + (tid >> 5);
    int f0 = (tid & 31) * 4;
    int i = i0 + ir;
    float m = (i < na) ? 1.f : 0.f;
    float4 v = *(const float4*)(x + ((size_t)b * cN + i) * cF + f0);
    bf16x4 pk = {(bf16)(v.x * m), (bf16)(v.y * m), (bf16)(v.z * m), (bf16)(v.w * m)};
    *(bf16x4*)(X0 + ((size_t)b * cN + i) * cF + f0) = pk;
    *(bf16x4*)(&T[ir][f0]) = pk;
  }
  __syncthreads();
  int f = tid >> 1, half = tid & 1;
  bf16* od = x0T + ((size_t)b * cF + f) * cN + i0 + half * 32;
#pragma unroll
  for (int c = 0; c < 32; c += 4) {
    int ii = half * 32 + c;
    bf16x4 pk = {T[ii][f], T[ii + 1][f], T[ii + 2][f], T[ii + 3][f]};
    *(bf16x4*)(od + c) = pk;
  }
}

// ---------------- k_wt: Wt[o][k*128+f]=weight[f*4+k][o]; MT[g][f]=M_L[f][g] --------
__global__ __launch_bounds__(256) void k_wt(const float* __restrict__ wgt,
                                            const float* __restrict__ ML,
                                            bf16* __restrict__ Wt,
                                            bf16* __restrict__ MT) {
  int id = blockIdx.x * 256 + threadIdx.x;
  if (id < 512 * 256) {
    int o = id >> 9, d = id & 511;
    int k = d >> 7, f = d & 127;
    Wt[id] = (bf16)wgt[(f * 4 + k) * 256 + o];
  } else {
    int id2 = id - 512 * 256;
    if (id2 < 128 * 128) {
      int g = id2 >> 7, f = id2 & 127;
      MT[id2] = (bf16)ML[f * 128 + g];
    }
  }
}

// ---------------- k_xwgram: xw(LDS) = X0@M_L; sq(LDS); gram -> Wb + deg -----------
// grid = 2 blocks/mol (i-halves); every block computes the full 256-row xw in LDS.
// LDS xw layout: row n (256B), byte col (2g) ^ ((n&7)<<4).
__global__ __launch_bounds__(512, 2) void k_xwgram(const bf16* __restrict__ X0,
                                                   const bf16* __restrict__ MT,
                                                   const int* __restrict__ na_p,
                                                   bf16* __restrict__ Wb16,
                                                   float* __restrict__ deg) {
  __shared__ __align__(16) char XW[65536];
  __shared__ float lsq[256];
  int bx = blockIdx.x;
  int b = bx >> 1, h = bx & 1;
  int tid = threadIdx.x, wid = tid >> 6, lane = tid & 63;
  int hi = lane >> 4, il = lane & 15;

  // ---- phase 1: xw rows [32*wid, 32*wid+32) ----
  const bf16* A = X0 + ((size_t)b * cN + wid * 32) * cF;
  f32x4 acc[2][8] = {};
#pragma unroll
  for (int ks = 0; ks < 4; ++ks) {
    int k0 = ks * 32;
    bf16x8 a0 = gfrag(A, cF, lane, k0);
    bf16x8 a1 = gfrag(A + 16 * cF, cF, lane, k0);
#pragma unroll
    for (int gt = 0; gt < 8; ++gt) {
      bf16x8 bb = gfrag(MT + (size_t)gt * 16 * 128, 128, lane, k0);
      acc[0][gt] = mfma(a0, bb, acc[0][gt]);
      acc[1][gt] = mfma(a1, bb, acc[1][gt]);
    }
  }
#pragma unroll
  for (int nt = 0; nt < 2; ++nt) {
#pragma unroll
    for (int r = 0; r < 4; ++r) {
      int n = 32 * wid + 16 * nt + 4 * hi + r;
      int swz = (n & 7) << 4;
      float s = 0.f;
#pragma unroll
      for (int gt = 0; gt < 8; ++gt) {
        bf16 v = (bf16)acc[nt][gt][r];
        *(bf16*)(XW + n * 256 + ((2 * (16 * gt + il)) ^ swz)) = v;
        float f = (float)v;
        s = fmaf(f, f, s);
      }
      s += __shfl_xor(s, 1); s += __shfl_xor(s, 2);
      s += __shfl_xor(s, 4); s += __shfl_xor(s, 8);
      if (il == 0) lsq[n] = s;
    }
  }
  __syncthreads();

  // ---- phase 2: gram for i in [128h + 16*wid, +16) vs all j ----
  int ibase = h * 128 + 16 * wid;
  int ia = ibase + il;
  f32x4 g2[16] = {};
#pragma unroll
  for (int ks = 0; ks < 4; ++ks) {
    int cb = 64 * ks + 16 * hi;
    bf16x8 af = *(const bf16x8*)(XW + ia * 256 + (cb ^ ((ia & 7) << 4)));
#pragma unroll
    for (int jt = 0; jt < 16; ++jt) {
      int j = 16 * jt + il;
      bf16x8 bf_ = *(const bf16x8*)(XW + j * 256 + (cb ^ ((j & 7) << 4)));
      g2[jt] = mfma(af, bf_, g2[jt]);
    }
  }
  int na = na_p[b];
#pragma unroll
  for (int r = 0; r < 4; ++r) {
    int i = ibase + 4 * hi + r;
    float sqi = lsq[i];
    bool mi = i < na;
    float rs = 0.f;
#pragma unroll
    for (int jt = 0; jt < 16; ++jt) {
      int j = 16 * jt + il;
      float w = 0.f;
      if (mi && j < na && i != j) {
        float d2 = fmaxf(sqi + lsq[j] - 2.f * g2[jt][r], D2_FLOOR);
        w = __expf(-sqrtf(d2));
      }
      Wb16[((size_t)b * cN + i) * cN + j] = (bf16)w;
      rs += w;
    }
    rs += __shfl_xor(rs, 1); rs += __shfl_xor(rs, 2);
    rs += __shfl_xor(rs, 4); rs += __shfl_xor(rs, 8);
    if (il == 0) deg[b * cN + i] = rs;
  }
}

// ---------------- k_Lassm: elementwise L assembly, 8 elems/thread ----------------
__global__ __launch_bounds__(256) void k_Lassm(const bf16* __restrict__ Wb16,
                                               const float* __restrict__ deg,
                                               const float* __restrict__ lap,
                                               const int* __restrict__ na_p,
                                               bf16* __restrict__ Lb,
                                               float* __restrict__ llearn) {
  int tid = threadIdx.x;
  size_t e = ((size_t)blockIdx.x * 256 + tid) * 8;   // 2048 elems = 8 rows per block
  int b = (int)(e >> 16);
  int na = na_p[b];
  __shared__ float dinvl[256];
  dinvl[tid] = (tid < na) ? 1.f / sqrtf(deg[b * cN + tid] + EPS_F) : 0.f;
  __syncthreads();
  int j = (int)(e & 255);
  int i = (int)((e >> 8) & 255);
  bf16x8 w8 = *(const bf16x8*)(Wb16 + e);
  float4 lp0 = *(const float4*)(lap + e);
  float4 lp1 = *(const float4*)(lap + e + 4);
  float di = dinvl[i];
  float mi = (i < na) ? 1.f : 0.f;
  float4 ll0, ll1;
  bf16x8 lo;
#pragma unroll
  for (int c = 0; c < 8; ++c) {
    int jj = j + c;
    float v = -di * (float)w8[c] * dinvl[jj];
    if (i == jj && i < na) v += 1.f;
    float lpv = (c < 4) ? (&lp0.x)[c] : (&lp1.x)[c - 4];
    if (c < 4) (&ll0.x)[c] = v; else (&ll1.x)[c - 4] = v;
    float mj = (jj < na) ? 1.f : 0.f;
    lo[c] = (bf16)(v + lpv * mi * mj);
  }
  *(float4*)(llearn + e) = ll0;
  *(float4*)(llearn + e + 4) = ll1;
  *(bf16x8*)(Lb + e) = lo;
}

// ---------------- k_chebout: 3 cheb steps + fused output GEMM ----------------
// States live in swizzled LDS [f][i] (row 512B, byte ^ ((f&7)<<4)).
// After each state is produced, its K=128 slice of out accumulates via MFMA:
//   A-frag (m=i rows, k=f) gathered from LDS; B = Wt rows o (global, L2-hot).
__device__ __forceinline__ void cheb_pass(const bf16* __restrict__ Lm,
                                          const char* Bsrc, const char* Ppp,
                                          char* Odst, int wid, int lane, bool haspp) {
  int hi = lane >> 4, il = lane & 15;
  int i0w = wid * 32;
  f32x4 acc[2][8] = {};
#pragma unroll
  for (int ks = 0; ks < 8; ++ks) {
    int k0 = ks * 32;
    bf16x8 a0 = gfrag(Lm + (size_t)i0w * cN, cN, lane, k0);
    bf16x8 a1 = gfrag(Lm + (size_t)(i0w + 16) * cN, cN, lane, k0);
#pragma unroll
    for (int nf = 0; nf < 8; ++nf) {
      int f = nf * 16 + il;
      const char* p = Bsrc + f * 512 + ((64 * ks + 16 * hi) ^ ((il & 7) << 4));
      bf16x8 bb = *(const bf16x8*)p;
      acc[0][nf] = mfma(a0, bb, acc[0][nf]);
      acc[1][nf] = mfma(a1, bb, acc[1][nf]);
    }
  }
#pragma unroll
  for (int mf = 0; mf < 2; ++mf) {
    int ib = i0w + mf * 16 + 4 * hi;
#pragma unroll
    for (int nf = 0; nf < 8; ++nf) {
      int f = nf * 16 + il;
      int cb = (2 * ib) ^ ((il & 7) << 4);
      bf16x4 o;
      if (haspp) {
        bf16x4 pp = *(const bf16x4*)(Ppp + f * 512 + cb);
#pragma unroll
        for (int r = 0; r < 4; ++r) o[r] = (bf16)(2.f * acc[mf][nf][r] - (float)pp[r]);
      } else {
#pragma unroll
        for (int r = 0; r < 4; ++r) o[r] = (bf16)acc[mf][nf][r];
      }
      *(bf16x4*)(Odst + f * 512 + cb) = o;
    }
  }
}

__global__ __launch_bounds__(512) void k_chebout(const bf16* __restrict__ x0T,
                                                 const bf16* __restrict__ Lb,
                                                 const bf16* __restrict__ Wt,
                                                 const float* __restrict__ bias,
                                                 const int* __restrict__ na_p,
                                                 float* __restrict__ out) {
  __shared__ __align__(16) char XB[2][65536];
  int b = blockIdx.x;
  int tid = threadIdx.x, wid = tid >> 6, lane = tid & 63;
  int hi = lane >> 4, il = lane & 15;
  const bf16* Lm = Lb + (size_t)b * cN * cN;
  const char* src = (const char*)(x0T + (size_t)b * cF * cN);

  f32x4 oacc[2][16] = {};   // [nt][ot] : rows i = 32*wid+16*nt+4*hi+r, cols o = 16*ot+il

  // load x0T (64KB) into XB[0], swizzled via pre-swizzled global source
#pragma unroll
  for (int it = 0; it < 8; ++it) {
    int beta = it * 8192 + tid * 16;
    int f = beta >> 9, c = beta & 511;
    gll16(src + f * 512 + (c ^ ((f & 7) << 4)), XB[0] + beta);
  }
  __syncthreads();

  // slice accumulation for state kst from LDS buffer Bsrc (own rows only)
#define SLICE(Bsrc, kst)                                                         \
  {                                                                              \
    const char* sb_ = (Bsrc);                                                    \
    _Pragma("unroll")                                                            \
    for (int ftp = 0; ftp < 4; ++ftp) {                                          \
      bf16x8 av[2];                                                              \
      _Pragma("unroll")                                                          \
      for (int nt = 0; nt < 2; ++nt) {                                           \
        int i_ = wid * 32 + nt * 16 + il;                                        \
        _Pragma("unroll")                                                        \
        for (int j = 0; j < 8; ++j) {                                            \
          int f_ = 32 * ftp + 8 * hi + j;                                        \
          av[nt][j] = *(const bf16*)(sb_ + f_ * 512 + ((2 * i_) ^ (j << 4)));    \
        }                                                                        \
      }                                                                          \
      _Pragma("unroll")                                                          \
      for (int ot = 0; ot < 16; ++ot) {                                          \
        bf16x8 bb = gfrag(Wt + (size_t)(16 * ot) * 512, 512, lane,               \
                          (kst) * 128 + 32 * ftp);                               \
        oacc[0][ot] = mfma(av[0], bb, oacc[0][ot]);                              \
        oacc[1][ot] = mfma(av[1], bb, oacc[1][ot]);                              \
      }                                                                          \
    }                                                                            \
  }

  SLICE(XB[0], 0);                                              // x0 slice
  cheb_pass(Lm, XB[0], nullptr, XB[1], wid, lane, false);       // x1 -> XB1
  SLICE(XB[1], 1);
  __syncthreads();
  cheb_pass(Lm, XB[1], XB[0], XB[0], wid, lane, true);          // x2 -> XB0 (pp=x0)
  SLICE(XB[0], 2);
  __syncthreads();
  cheb_pass(Lm, XB[0], XB[1], XB[1], wid, lane, true);          // x3 -> XB1 (pp=x1)
  SLICE(XB[1], 3);
#undef SLICE

  // epilogue: bias + mask + relu + store
  int na = na_p[b];
#pragma unroll
  for (int ot = 0; ot < 16; ++ot) {
    int o = 16 * ot + il;
    float bo = bias[o];
#pragma unroll
    for (int nt = 0; nt < 2; ++nt) {
#pragma unroll
      for (int r = 0; r < 4; ++r) {
        int n = wid * 32 + nt * 16 + 4 * hi + r;
        float m = (n < na) ? 1.f : 0.f;
        out[((size_t)b * cN + n) * cO + o] = fmaxf((oacc[nt][ot][r] + bo) * m, 0.f);
      }
    }
  }
}

// ---------------- launcher ----------------
extern "C" void kernel_launch(void* const* d_in, const int* in_sizes, int n_in,
                              void* d_out, int out_size, void* d_ws, size_t ws_size,
                              hipStream_t stream) {
  const float* x    = (const float*)d_in[0];
  const float* lap  = (const float*)d_in[1];
  const int*   na   = (const int*)d_in[2];
  const float* M_L  = (const float*)d_in[3];
  const float* wgt  = (const float*)d_in[4];
  const float* bias = (const float*)d_in[5];

  float* out    = (float*)d_out;
  float* llearn = out + (size_t)BN * cO;

  char* ws = (char*)d_ws;
  bf16*  X0  = (bf16*)(ws + OFF_X0);
  bf16*  x0T = (bf16*)(ws + OFF_X0T);
  bf16*  Lb  = (bf16*)(ws + OFF_LB);
  bf16*  Wb  = (bf16*)(ws + OFF_WB);
  bf16*  Wt  = (bf16*)(ws + OFF_WT);
  bf16*  MT  = (bf16*)(ws + OFF_MT);
  float* deg = (float*)(ws + OFF_DEG);

  k_prep<<<dim3(1024), 256, 0, stream>>>(x, na, X0, x0T);
  k_wt<<<dim3(576), 256, 0, stream>>>(wgt, M_L, Wt, MT);
  k_xwgram<<<dim3(512), 512, 0, stream>>>(X0, MT, na, Wb, deg);
  k_Lassm<<<dim3(8192), 256, 0, stream>>>(Wb, deg, lap, na, Lb, llearn);
  k_chebout<<<dim3(cB), 512, 0, stream>>>(x0T, Lb, Wt, bias, na, out);
}